// Round 10
// baseline (242.610 us; speedup 1.0000x reference)
//
#include <hip/hip_runtime.h>
#include <hip/hip_bf16.h>

typedef __hip_bfloat16 bf16;
typedef __fp16 half2_t __attribute__((ext_vector_type(2)));
typedef float floatx2 __attribute__((ext_vector_type(2)));

#define N_NODES 20000
#define N_EDGES 320000
#define CSTF 1e-5f

#if defined(__has_builtin)
#if __has_builtin(__builtin_amdgcn_cvt_pk_fp8_f32) && __has_builtin(__builtin_amdgcn_cvt_pk_f32_fp8)
#define M1FP8 1
#endif
#if __has_builtin(__builtin_amdgcn_fdot2)
#define HAVE_FDOT2 1
#endif
#endif

__device__ __forceinline__ half2_t u2h(unsigned int u) {
    union { unsigned int u; half2_t h; } c; c.u = u; return c.h;
}
__device__ __forceinline__ unsigned int pkh(float a, float b) {
    union { __fp16 h[2]; unsigned int u; } c;
    c.h[0] = (__fp16)a; c.h[1] = (__fp16)b;
    return c.u;
}
__device__ __forceinline__ float fdot2(half2_t a, half2_t b, float c) {
#ifdef HAVE_FDOT2
    return __builtin_amdgcn_fdot2(a, b, c, false);
#else
    return fmaf((float)a.x, (float)b.x, fmaf((float)a.y, (float)b.y, c));
#endif
}
__device__ __forceinline__ int rdl(int v, int lane) { return __builtin_amdgcn_readlane(v, lane); }
__device__ __forceinline__ float rdlf(float v, int lane) {
    return __int_as_float(__builtin_amdgcn_readlane(__float_as_int(v), lane));
}

__device__ __forceinline__ float ldf(const void* p, int i, bool bf) {
    return bf ? __bfloat162float(((const bf16*)p)[i]) : ((const float*)p)[i];
}

// Per-wave int64-vs-int32 self-detection (see R7 notes).
__device__ __forceinline__ bool wave_is_i64(const void* ei, int e) {
    unsigned int hi = ((const unsigned int*)ei)[2 * e + 1];
    return !__any(hi != 0);
}

// ---------------------------------------------------------------------------
// Phase 1: in-degree count over col + sampled x-dtype detection
__global__ __launch_bounds__(256) void k_p1(const unsigned int* __restrict__ xs,
                                            const void* __restrict__ ei,
                                            int* __restrict__ deg, int* __restrict__ cnt) {
    const int e = blockIdx.x * 256 + threadIdx.x;
    bool i64 = wave_is_i64(ei, e);
    int c = i64 ? (int)((const long long*)ei)[N_EDGES + e] : ((const int*)ei)[N_EDGES + e];
    atomicAdd(&deg[c], 1);
    if (blockIdx.x < 64) {
        int t = blockIdx.x * 256 + threadIdx.x;
        int bad = 0;
        for (int i = t; i < 40000; i += 64 * 256) {
            unsigned int w = xs[i];
            if (((w >> 7)  & 0xFFu) == 0xFFu) bad++;
            if (((w >> 23) & 0xFFu) == 0xFFu) bad++;
        }
        if (bad) atomicAdd(&cnt[0], bad);
    }
}

// Exclusive scan of deg -> rowptr + deg^-0.5 (single block)
__global__ __launch_bounds__(1024) void k_scan(const int* __restrict__ deg, int* __restrict__ rowptr,
                                               float* __restrict__ deg_inv) {
    __shared__ int part[1024];
    const int t = threadIdx.x;
    const int CH = (N_NODES + 1023) / 1024;  // 20
    int base = t * CH;
    int s = 0;
    for (int i = 0; i < CH; i++) {
        int idx = base + i;
        if (idx < N_NODES) {
            int d = deg[idx];
            s += d;
            deg_inv[idx] = d > 0 ? rsqrtf((float)d) : 0.0f;
        }
    }
    part[t] = s;
    __syncthreads();
    for (int off = 1; off < 1024; off <<= 1) {
        int v = (t >= off) ? part[t - off] : 0;
        __syncthreads();
        part[t] += v;
        __syncthreads();
    }
    int ex = (t == 0) ? 0 : part[t - 1];
    for (int i = 0; i < CH; i++) {
        int idx = base + i;
        if (idx < N_NODES) { rowptr[idx] = ex; ex += deg[idx]; }
    }
    if (t == 1023) rowptr[N_NODES] = part[1023];
}

// ---------------------------------------------------------------------------
// Phase 2 (fused): blocks [0,625) QKV; blocks [625,1875) CSR fill
// QKV: weights staged in LDS as packed-f16, COLUMN-major (sW[col][kkpair],
// stride 33 uints to spread banks); x row staged fp32 in LDS, read as float2
// broadcast + cvt_pkrtz; 3 fdot2 per k-pair.
#define QKV_BLOCKS 625
#define WSTRIDE 33
__global__ __launch_bounds__(256) void k_p2(const void* __restrict__ x,
                                            const void* __restrict__ Wq, const void* __restrict__ bq,
                                            const void* __restrict__ Wk, const void* __restrict__ bk,
                                            const void* __restrict__ Wv, const void* __restrict__ bv,
                                            float* __restrict__ Q, _Float16* __restrict__ K0h,
                                            _Float16* __restrict__ Vh,
                                            const void* __restrict__ ei,
                                            const float* __restrict__ deg_inv,
                                            const int* __restrict__ rowptr,
                                            int* __restrict__ fill, int* __restrict__ csr_src,
                                            float* __restrict__ csr_w,
                                            const int* __restrict__ cnt) {
    __shared__ unsigned int sWq[64 * WSTRIDE];
    __shared__ unsigned int sWk[64 * WSTRIDE];
    __shared__ unsigned int sWv[64 * WSTRIDE];
    __shared__ float sx[4][64];
    const int t = threadIdx.x;
    if (blockIdx.x >= QKV_BLOCKS) {
        const int e = (blockIdx.x - QKV_BLOCKS) * 256 + t;
        bool i64 = wave_is_i64(ei, e);
        int r, c;
        if (i64) {
            r = (int)((const long long*)ei)[e];
            c = (int)((const long long*)ei)[N_EDGES + e];
        } else {
            r = ((const int*)ei)[e];
            c = ((const int*)ei)[N_EDGES + e];
        }
        int slot = rowptr[c] + atomicAdd(&fill[c], 1);
        csr_src[slot] = r;
        csr_w[slot] = deg_inv[r] * deg_inv[c];
        return;
    }
    const bool bf = (cnt[0] < 16);
    // stage W^T packed f16: sW[col*WSTRIDE + kp] = (W[2kp][col], W[2kp+1][col])
    for (int i = t; i < 2048; i += 256) {
        int col = i >> 5, kp = i & 31;
        sWq[col * WSTRIDE + kp] = pkh(ldf(Wq, 2 * kp * 64 + col, bf), ldf(Wq, (2 * kp + 1) * 64 + col, bf));
        sWk[col * WSTRIDE + kp] = pkh(ldf(Wk, 2 * kp * 64 + col, bf), ldf(Wk, (2 * kp + 1) * 64 + col, bf));
        sWv[col * WSTRIDE + kp] = pkh(ldf(Wv, 2 * kp * 64 + col, bf), ldf(Wv, (2 * kp + 1) * 64 + col, bf));
    }
    __syncthreads();
    const int lane = t & 63, sub = t >> 6;
    const float bqv = ldf(bq, lane, bf), bkv = ldf(bk, lane, bf), bvv = ldf(bv, lane, bf);
    const unsigned int* wq = sWq + lane * WSTRIDE;
    const unsigned int* wk = sWk + lane * WSTRIDE;
    const unsigned int* wv = sWv + lane * WSTRIDE;
    const int npb = (N_NODES + QKV_BLOCKS - 1) / QKV_BLOCKS;  // 32
    const int n0 = blockIdx.x * npb;
    const int n1 = min(n0 + npb, N_NODES);
    for (int nb = n0; nb < n1; nb += 4) {
        int n = nb + sub;
        __syncthreads();
        if (n < n1) sx[sub][lane] = ldf(x, n * 64 + lane, bf);
        __syncthreads();
        if (n < n1) {
            float q = bqv, k = bkv, v = bvv;
            const float2* xp = (const float2*)sx[sub];
#pragma unroll 8
            for (int kp = 0; kp < 32; kp++) {
                float2 xv = xp[kp];
                half2_t xh = u2h(pkh(xv.x, xv.y));
                q = fdot2(xh, u2h(wq[kp]), q);
                k = fdot2(xh, u2h(wk[kp]), k);
                v = fdot2(xh, u2h(wv[kp]), v);
            }
            Q[n * 64 + lane]   = q > 0.0f ? q + 1.0f : __expf(q);
            K0h[n * 64 + lane] = (_Float16)(k > 0.0f ? k + 1.0f : __expf(k));
            Vh[n * 64 + lane]  = (_Float16)v;
        }
    }
}

// ---------------------------------------------------------------------------
// M1 store helpers: fp8 (e4m3, node stride 128 uints) or f16 fallback (256)
#ifdef M1FP8
#define M1_STRIDE 128
#define M1_LANE   2
#else
#define M1_STRIDE 256
#define M1_LANE   4
#endif

// Hop 1. One node per wave, 128-thr blocks. Lane l = (h = l>>3, j = l&7).
__global__ __launch_bounds__(128) void k_hop1(const _Float16* __restrict__ K0h,
                                              const _Float16* __restrict__ Vh,
                                              const int* __restrict__ rowptr,
                                              const int* __restrict__ csr_src,
                                              const float* __restrict__ csr_w,
                                              unsigned int* __restrict__ M1h,
                                              _Float16* __restrict__ K1h) {
    const int l = threadIdx.x & 63;
    const int n = blockIdx.x * 2 + (threadIdx.x >> 6);
    const int hb = l & 56;
    float acc[8] = {0, 0, 0, 0, 0, 0, 0, 0};
    float kacc = 0.0f;
    const int s0 = rowptr[n], s1 = rowptr[n + 1];

#define H1_BODY(KU, VO, KO, EE)                                            \
    {                                                                      \
        float w = rdlf(wv, EE);                                            \
        half2_t p0 = u2h(KU.x), p1 = u2h(KU.y), p2 = u2h(KU.z), p3 = u2h(KU.w); \
        float wvv = w * (float)VO;                                         \
        acc[0] = fmaf(wvv, (float)p0.x, acc[0]); acc[1] = fmaf(wvv, (float)p0.y, acc[1]); \
        acc[2] = fmaf(wvv, (float)p1.x, acc[2]); acc[3] = fmaf(wvv, (float)p1.y, acc[3]); \
        acc[4] = fmaf(wvv, (float)p2.x, acc[4]); acc[5] = fmaf(wvv, (float)p2.y, acc[5]); \
        acc[6] = fmaf(wvv, (float)p3.x, acc[6]); acc[7] = fmaf(wvv, (float)p3.y, acc[7]); \
        kacc = fmaf(w, (float)KO, kacc);                                   \
    }

    for (int c = s0; c < s1; c += 64) {
        const int m = min(64, s1 - c);
        const int idx = c + (l < m ? l : m - 1);
        const int srcv = csr_src[idx];
        const float wv = csr_w[idx];
        int e = 0;
        for (; e + 4 <= m; e += 4) {
            int sA = rdl(srcv, e), sB = rdl(srcv, e + 1), sC = rdl(srcv, e + 2), sD = rdl(srcv, e + 3);
            uint4 kA = *(const uint4*)(K0h + sA * 64 + hb);
            uint4 kB = *(const uint4*)(K0h + sB * 64 + hb);
            uint4 kC = *(const uint4*)(K0h + sC * 64 + hb);
            uint4 kD = *(const uint4*)(K0h + sD * 64 + hb);
            __fp16 vA = Vh[sA * 64 + l], vB = Vh[sB * 64 + l], vC = Vh[sC * 64 + l], vD = Vh[sD * 64 + l];
            __fp16 oA = K0h[sA * 64 + l], oB = K0h[sB * 64 + l], oC = K0h[sC * 64 + l], oD = K0h[sD * 64 + l];
            H1_BODY(kA, vA, oA, e)
            H1_BODY(kB, vB, oB, e + 1)
            H1_BODY(kC, vC, oC, e + 2)
            H1_BODY(kD, vD, oD, e + 3)
        }
        for (; e < m; e++) {
            int sA = rdl(srcv, e);
            uint4 kA = *(const uint4*)(K0h + sA * 64 + hb);
            __fp16 vA = Vh[sA * 64 + l];
            __fp16 oA = K0h[sA * 64 + l];
            H1_BODY(kA, vA, oA, e)
        }
    }
#undef H1_BODY

#ifdef M1FP8
    unsigned int w0 = 0, w1 = 0;
    w0 = __builtin_amdgcn_cvt_pk_fp8_f32(acc[0], acc[1], w0, false);
    w0 = __builtin_amdgcn_cvt_pk_fp8_f32(acc[2], acc[3], w0, true);
    w1 = __builtin_amdgcn_cvt_pk_fp8_f32(acc[4], acc[5], w1, false);
    w1 = __builtin_amdgcn_cvt_pk_fp8_f32(acc[6], acc[7], w1, true);
    uint2 o2; o2.x = w0; o2.y = w1;
    *(uint2*)(M1h + (size_t)n * M1_STRIDE + l * M1_LANE) = o2;
#else
    uint4 o;
    o.x = pkh(acc[0], acc[1]); o.y = pkh(acc[2], acc[3]);
    o.z = pkh(acc[4], acc[5]); o.w = pkh(acc[6], acc[7]);
    *(uint4*)(M1h + (size_t)n * M1_STRIDE + l * M1_LANE) = o;
#endif
    K1h[n * 64 + l] = (_Float16)kacc;
}

// ---------------------------------------------------------------------------
// Hop 2 + finalize. One node per wave, 128-thr blocks. Lane l = (h, j').
__global__ __launch_bounds__(128) void k_hop2f(const float* __restrict__ Q,
                                               const unsigned int* __restrict__ M1h,
                                               const _Float16* __restrict__ K1h,
                                               const _Float16* __restrict__ Vh,
                                               const int* __restrict__ rowptr,
                                               const int* __restrict__ csr_src,
                                               const float* __restrict__ csr_w,
                                               const void* __restrict__ Wo, const void* __restrict__ bo,
                                               const void* __restrict__ hopwise,
                                               const void* __restrict__ headwise,
                                               void* __restrict__ out, const int* __restrict__ cnt) {
    const bool bf = (cnt[0] < 16);
    const int l = threadIdx.x & 63;
    const int n = blockIdx.x * 2 + (threadIdx.x >> 6);
    const int hb = l & 56, h = l >> 3;
    const float4 qa = *(const float4*)(Q + n * 64 + hb);
    const float4 qb = *(const float4*)(Q + n * 64 + hb + 4);
    const float qown = Q[n * 64 + l];
    float hacc = 0.0f, sk = 0.0f;
    const int s0 = rowptr[n], s1 = rowptr[n + 1];

#ifdef M1FP8
#define H2_DOT(MU, DST)                                                    \
    {                                                                      \
        floatx2 a0 = __builtin_amdgcn_cvt_pk_f32_fp8(MU.x, false);         \
        floatx2 a1 = __builtin_amdgcn_cvt_pk_f32_fp8(MU.x, true);          \
        floatx2 a2 = __builtin_amdgcn_cvt_pk_f32_fp8(MU.y, false);         \
        floatx2 a3 = __builtin_amdgcn_cvt_pk_f32_fp8(MU.y, true);          \
        DST = qa.x * a0.x;                                                 \
        DST = fmaf(qa.y, a0.y, DST); DST = fmaf(qa.z, a1.x, DST);          \
        DST = fmaf(qa.w, a1.y, DST); DST = fmaf(qb.x, a2.x, DST);          \
        DST = fmaf(qb.y, a2.y, DST); DST = fmaf(qb.z, a3.x, DST);          \
        DST = fmaf(qb.w, a3.y, DST);                                       \
    }
    typedef uint2 m1vec;
#else
    const half2_t q01 = u2h(pkh(qa.x, qa.y));
    const half2_t q23 = u2h(pkh(qa.z, qa.w));
    const half2_t q45 = u2h(pkh(qb.x, qb.y));
    const half2_t q67 = u2h(pkh(qb.z, qb.w));
#define H2_DOT(MU, DST)                                                    \
    {                                                                      \
        DST = fdot2(q01, u2h(MU.x), 0.0f);                                 \
        DST = fdot2(q23, u2h(MU.y), DST);                                  \
        DST = fdot2(q45, u2h(MU.z), DST);                                  \
        DST = fdot2(q67, u2h(MU.w), DST);                                  \
    }
    typedef uint4 m1vec;
#endif

    for (int c = s0; c < s1; c += 64) {
        const int m = min(64, s1 - c);
        const int idx = c + (l < m ? l : m - 1);
        const int srcv = csr_src[idx];
        const float wv = csr_w[idx];
        int e = 0;
        for (; e + 4 <= m; e += 4) {
            int sA = rdl(srcv, e), sB = rdl(srcv, e + 1), sC = rdl(srcv, e + 2), sD = rdl(srcv, e + 3);
            m1vec mA = *(const m1vec*)(M1h + (size_t)sA * M1_STRIDE + l * M1_LANE);
            m1vec mB = *(const m1vec*)(M1h + (size_t)sB * M1_STRIDE + l * M1_LANE);
            m1vec mC = *(const m1vec*)(M1h + (size_t)sC * M1_STRIDE + l * M1_LANE);
            m1vec mD = *(const m1vec*)(M1h + (size_t)sD * M1_STRIDE + l * M1_LANE);
            __fp16 kA = K1h[sA * 64 + l], kB = K1h[sB * 64 + l], kC = K1h[sC * 64 + l], kD = K1h[sD * 64 + l];
            float d;
            H2_DOT(mA, d) { float w = rdlf(wv, e);     hacc = fmaf(w, d, hacc); sk = fmaf(w, (float)kA, sk); }
            H2_DOT(mB, d) { float w = rdlf(wv, e + 1); hacc = fmaf(w, d, hacc); sk = fmaf(w, (float)kB, sk); }
            H2_DOT(mC, d) { float w = rdlf(wv, e + 2); hacc = fmaf(w, d, hacc); sk = fmaf(w, (float)kC, sk); }
            H2_DOT(mD, d) { float w = rdlf(wv, e + 3); hacc = fmaf(w, d, hacc); sk = fmaf(w, (float)kD, sk); }
        }
        for (; e < m; e++) {
            int sA = rdl(srcv, e);
            m1vec mA = *(const m1vec*)(M1h + (size_t)sA * M1_STRIDE + l * M1_LANE);
            __fp16 kA = K1h[sA * 64 + l];
            float d;
            H2_DOT(mA, d) { float w = rdlf(wv, e); hacc = fmaf(w, d, hacc); sk = fmaf(w, (float)kA, sk); }
        }
    }
    m1vec mo = *(const m1vec*)(M1h + (size_t)n * M1_STRIDE + l * M1_LANE);
    float h1;
    H2_DOT(mo, h1)
#undef H2_DOT
    float c1 = qown * (float)K1h[n * 64 + l];
    float c2 = qown * sk;
#pragma unroll
    for (int dd = 1; dd < 8; dd <<= 1) {
        c1 += __shfl_xor(c1, dd);
        c2 += __shfl_xor(c2, dd);
    }
    float hw0 = ldf(hopwise, 0, bf), hw1 = ldf(hopwise, 1, bf), hw2 = ldf(hopwise, 2, bf);
    float e0 = 0.0f, e1 = 0.0f;
#pragma unroll
    for (int hh = 0; hh < 8; hh++) {
        e0 += __expf(ldf(headwise, hh * 2 + 0, bf));
        e1 += __expf(ldf(headwise, hh * 2 + 1, bf));
    }
    float g1 = hw1 * __expf(ldf(headwise, h * 2 + 0, bf)) / e0;
    float g2 = hw2 * __expf(ldf(headwise, h * 2 + 1, bf)) / e1;

    float hidden = hw0 * (float)Vh[n * 64 + l] + g1 * h1 / (c1 + CSTF) + g2 * hacc / (c2 + CSTF);

    float o = ldf(bo, l, bf);
#pragma unroll 16
    for (int k = 0; k < 64; k++) {
        float hk = __shfl(hidden, k);
        o += hk * ldf(Wo, k * 64 + l, bf);
    }
    if (bf) ((bf16*)out)[n * 64 + l] = __float2bfloat16(o);
    else    ((float*)out)[n * 64 + l] = o;
}

// ---------------------------------------------------------------------------
extern "C" void kernel_launch(void* const* d_in, const int* in_sizes, int n_in,
                              void* d_out, int out_size, void* d_ws, size_t ws_size,
                              hipStream_t stream) {
    const void* x        = d_in[0];
    const void* ei       = d_in[1];
    const void* Wq       = d_in[3];
    const void* bq       = d_in[4];
    const void* Wk       = d_in[5];
    const void* bk       = d_in[6];
    const void* Wv       = d_in[7];
    const void* bv       = d_in[8];
    const void* Wo       = d_in[9];
    const void* bo       = d_in[10];
    const void* hopwise  = d_in[11];
    const void* headwise = d_in[12];

    char* p = (char*)d_ws;
    auto alloc = [&](size_t bytes) {
        void* r = (void*)p;
        p += (bytes + 255) & ~(size_t)255;
        return r;
    };
    float* Q          = (float*)alloc((size_t)N_NODES * 64 * 4);
    float* deg_inv    = (float*)alloc((size_t)N_NODES * 4);
    _Float16* K0h     = (_Float16*)alloc((size_t)N_NODES * 64 * 2);
    _Float16* Vh      = (_Float16*)alloc((size_t)N_NODES * 64 * 2);
    _Float16* K1h     = (_Float16*)alloc((size_t)N_NODES * 64 * 2);
    unsigned int* M1h = (unsigned int*)alloc((size_t)N_NODES * 1024);
    float* csr_w      = (float*)alloc((size_t)N_EDGES * 4);
    int* csr_src      = (int*)alloc((size_t)N_EDGES * 4);
    int* rowptr       = (int*)alloc((size_t)(N_NODES + 1) * 4);
    int* zz           = (int*)alloc(((size_t)2 * N_NODES + 64) * 4);
    int* deg  = zz;
    int* fill = zz + N_NODES;
    int* cnt  = zz + 2 * N_NODES;

    (void)hipMemsetAsync(zz, 0, ((size_t)2 * N_NODES + 64) * 4, stream);

    const int EB = (N_EDGES + 255) / 256;  // 1250

    k_p1<<<EB, 256, 0, stream>>>((const unsigned int*)x, ei, deg, cnt);
    k_scan<<<1, 1024, 0, stream>>>(deg, rowptr, deg_inv);
    k_p2<<<QKV_BLOCKS + EB, 256, 0, stream>>>(x, Wq, bq, Wk, bk, Wv, bv, Q, K0h, Vh,
                                              ei, deg_inv, rowptr, fill, csr_src, csr_w, cnt);
    k_hop1<<<N_NODES / 2, 128, 0, stream>>>(K0h, Vh, rowptr, csr_src, csr_w, M1h, K1h);
    k_hop2f<<<N_NODES / 2, 128, 0, stream>>>(Q, M1h, K1h, Vh, rowptr, csr_src, csr_w,
                                             Wo, bo, hopwise, headwise, d_out, cnt);
}

// Round 11
// 239.076 us; speedup vs baseline: 1.0148x; 1.0148x over previous
//
#include <hip/hip_runtime.h>
#include <hip/hip_bf16.h>

typedef __hip_bfloat16 bf16;
typedef __fp16 half2_t __attribute__((ext_vector_type(2)));
typedef float floatx2 __attribute__((ext_vector_type(2)));

#define N_NODES 20000
#define N_EDGES 320000
#define CSTF 1e-5f

#if defined(__has_builtin)
#if __has_builtin(__builtin_amdgcn_cvt_pk_fp8_f32) && __has_builtin(__builtin_amdgcn_cvt_pk_f32_fp8)
#define M1FP8 1
#endif
#if __has_builtin(__builtin_amdgcn_fdot2)
#define HAVE_FDOT2 1
#endif
#endif

__device__ __forceinline__ half2_t u2h(unsigned int u) {
    union { unsigned int u; half2_t h; } c; c.u = u; return c.h;
}
__device__ __forceinline__ unsigned int pkh(float a, float b) {
    union { __fp16 h[2]; unsigned int u; } c;
    c.h[0] = (__fp16)a; c.h[1] = (__fp16)b;
    return c.u;
}
__device__ __forceinline__ float fdot2(half2_t a, half2_t b, float c) {
#ifdef HAVE_FDOT2
    return __builtin_amdgcn_fdot2(a, b, c, false);
#else
    return fmaf((float)a.x, (float)b.x, fmaf((float)a.y, (float)b.y, c));
#endif
}
__device__ __forceinline__ int rdl(int v, int lane) { return __builtin_amdgcn_readlane(v, lane); }
__device__ __forceinline__ float rdlf(float v, int lane) {
    return __int_as_float(__builtin_amdgcn_readlane(__float_as_int(v), lane));
}

__device__ __forceinline__ float ldf(const void* p, int i, bool bf) {
    return bf ? __bfloat162float(((const bf16*)p)[i]) : ((const float*)p)[i];
}

// Per-wave int64-vs-int32 self-detection (see R7 notes).
__device__ __forceinline__ bool wave_is_i64(const void* ei, int e) {
    unsigned int hi = ((const unsigned int*)ei)[2 * e + 1];
    return !__any(hi != 0);
}

// ---------------------------------------------------------------------------
// Phase 1: in-degree count over col + sampled x-dtype detection
__global__ __launch_bounds__(256) void k_p1(const unsigned int* __restrict__ xs,
                                            const void* __restrict__ ei,
                                            int* __restrict__ deg, int* __restrict__ cnt) {
    const int e = blockIdx.x * 256 + threadIdx.x;
    bool i64 = wave_is_i64(ei, e);
    int c = i64 ? (int)((const long long*)ei)[N_EDGES + e] : ((const int*)ei)[N_EDGES + e];
    atomicAdd(&deg[c], 1);
    if (blockIdx.x < 64) {
        int t = blockIdx.x * 256 + threadIdx.x;
        int bad = 0;
        for (int i = t; i < 40000; i += 64 * 256) {
            unsigned int w = xs[i];
            if (((w >> 7)  & 0xFFu) == 0xFFu) bad++;
            if (((w >> 23) & 0xFFu) == 0xFFu) bad++;
        }
        if (bad) atomicAdd(&cnt[0], bad);
    }
}

// Exclusive scan of deg -> rowptr + deg^-0.5 (single block)
__global__ __launch_bounds__(1024) void k_scan(const int* __restrict__ deg, int* __restrict__ rowptr,
                                               float* __restrict__ deg_inv) {
    __shared__ int part[1024];
    const int t = threadIdx.x;
    const int CH = (N_NODES + 1023) / 1024;  // 20
    int base = t * CH;
    int s = 0;
    for (int i = 0; i < CH; i++) {
        int idx = base + i;
        if (idx < N_NODES) {
            int d = deg[idx];
            s += d;
            deg_inv[idx] = d > 0 ? rsqrtf((float)d) : 0.0f;
        }
    }
    part[t] = s;
    __syncthreads();
    for (int off = 1; off < 1024; off <<= 1) {
        int v = (t >= off) ? part[t - off] : 0;
        __syncthreads();
        part[t] += v;
        __syncthreads();
    }
    int ex = (t == 0) ? 0 : part[t - 1];
    for (int i = 0; i < CH; i++) {
        int idx = base + i;
        if (idx < N_NODES) { rowptr[idx] = ex; ex += deg[idx]; }
    }
    if (t == 1023) rowptr[N_NODES] = part[1023];
}

// ---------------------------------------------------------------------------
// Phase 2 (fused): blocks [0,2500) QKV (8 nodes each); rest CSR fill.
// Weights staged packed-f16 [kp][col] stride 64: staging reads coalesced
// (col = fast index), consumer sW[kp*64+lane] is 2-way bank alias (free).
#define QKV_BLOCKS 2500
__global__ __launch_bounds__(256) void k_p2(const void* __restrict__ x,
                                            const void* __restrict__ Wq, const void* __restrict__ bq,
                                            const void* __restrict__ Wk, const void* __restrict__ bk,
                                            const void* __restrict__ Wv, const void* __restrict__ bv,
                                            float* __restrict__ Q, _Float16* __restrict__ K0h,
                                            _Float16* __restrict__ Vh,
                                            const void* __restrict__ ei,
                                            const float* __restrict__ deg_inv,
                                            const int* __restrict__ rowptr,
                                            int* __restrict__ fill, int* __restrict__ csr_src,
                                            float* __restrict__ csr_w,
                                            const int* __restrict__ cnt) {
    __shared__ unsigned int sWq[2048];
    __shared__ unsigned int sWk[2048];
    __shared__ unsigned int sWv[2048];
    __shared__ float sx[4][64];
    const int t = threadIdx.x;
    if (blockIdx.x >= QKV_BLOCKS) {
        const int e = (blockIdx.x - QKV_BLOCKS) * 256 + t;
        bool i64 = wave_is_i64(ei, e);
        int r, c;
        if (i64) {
            r = (int)((const long long*)ei)[e];
            c = (int)((const long long*)ei)[N_EDGES + e];
        } else {
            r = ((const int*)ei)[e];
            c = ((const int*)ei)[N_EDGES + e];
        }
        int slot = rowptr[c] + atomicAdd(&fill[c], 1);
        csr_src[slot] = r;
        csr_w[slot] = deg_inv[r] * deg_inv[c];
        return;
    }
    const bool bf = (cnt[0] < 16);
    // coalesced staging: i -> kp = i>>6 (slow), col = i&63 (fast)
    for (int i = t; i < 2048; i += 256) {
        int kp = i >> 6, col = i & 63;
        sWq[i] = pkh(ldf(Wq, 2 * kp * 64 + col, bf), ldf(Wq, (2 * kp + 1) * 64 + col, bf));
        sWk[i] = pkh(ldf(Wk, 2 * kp * 64 + col, bf), ldf(Wk, (2 * kp + 1) * 64 + col, bf));
        sWv[i] = pkh(ldf(Wv, 2 * kp * 64 + col, bf), ldf(Wv, (2 * kp + 1) * 64 + col, bf));
    }
    __syncthreads();
    const int lane = t & 63, sub = t >> 6;
    const float bqv = ldf(bq, lane, bf), bkv = ldf(bk, lane, bf), bvv = ldf(bv, lane, bf);
    const int n0 = blockIdx.x * 8;
    const int n1 = min(n0 + 8, N_NODES);
    for (int nb = n0; nb < n1; nb += 4) {
        int n = nb + sub;
        __syncthreads();
        if (n < n1) sx[sub][lane] = ldf(x, n * 64 + lane, bf);
        __syncthreads();
        if (n < n1) {
            float q = bqv, k = bkv, v = bvv;
            const float2* xp = (const float2*)sx[sub];
#pragma unroll 8
            for (int kp = 0; kp < 32; kp++) {
                float2 xv = xp[kp];
                half2_t xh = u2h(pkh(xv.x, xv.y));
                q = fdot2(xh, u2h(sWq[kp * 64 + lane]), q);
                k = fdot2(xh, u2h(sWk[kp * 64 + lane]), k);
                v = fdot2(xh, u2h(sWv[kp * 64 + lane]), v);
            }
            Q[n * 64 + lane]   = q > 0.0f ? q + 1.0f : __expf(q);
            K0h[n * 64 + lane] = (_Float16)(k > 0.0f ? k + 1.0f : __expf(k));
            Vh[n * 64 + lane]  = (_Float16)v;
        }
    }
}

// ---------------------------------------------------------------------------
// M1 store helpers: fp8 (e4m3, node stride 128 uints) or f16 fallback (256)
#ifdef M1FP8
#define M1_STRIDE 128
#define M1_LANE   2
#else
#define M1_STRIDE 256
#define M1_LANE   4
#endif

// Hop 1. One node per wave, 128-thr blocks. Lane l = (h = l>>3, j = l&7).
// kown (= K0[src][l]) is element j of the loaded ku row -> cndmask extract,
// no separate VMEM (2 VMEM/edge total).
__global__ __launch_bounds__(128) void k_hop1(const _Float16* __restrict__ K0h,
                                              const _Float16* __restrict__ Vh,
                                              const int* __restrict__ rowptr,
                                              const int* __restrict__ csr_src,
                                              const float* __restrict__ csr_w,
                                              unsigned int* __restrict__ M1h,
                                              _Float16* __restrict__ K1h) {
    const int l = threadIdx.x & 63;
    const int n = blockIdx.x * 2 + (threadIdx.x >> 6);
    const int hb = l & 56;
    const int j = l & 7;
    float acc[8] = {0, 0, 0, 0, 0, 0, 0, 0};
    float kacc = 0.0f;
    const int s0 = rowptr[n], s1 = rowptr[n + 1];

#define H1_BODY(KU, VO, EE)                                                \
    {                                                                      \
        float w = rdlf(wv, EE);                                            \
        half2_t p0 = u2h(KU.x), p1 = u2h(KU.y), p2 = u2h(KU.z), p3 = u2h(KU.w); \
        float f0 = (float)p0.x, f1 = (float)p0.y, f2 = (float)p1.x, f3 = (float)p1.y; \
        float f4 = (float)p2.x, f5 = (float)p2.y, f6 = (float)p3.x, f7 = (float)p3.y; \
        float wvv = w * (float)VO;                                         \
        acc[0] = fmaf(wvv, f0, acc[0]); acc[1] = fmaf(wvv, f1, acc[1]);    \
        acc[2] = fmaf(wvv, f2, acc[2]); acc[3] = fmaf(wvv, f3, acc[3]);    \
        acc[4] = fmaf(wvv, f4, acc[4]); acc[5] = fmaf(wvv, f5, acc[5]);    \
        acc[6] = fmaf(wvv, f6, acc[6]); acc[7] = fmaf(wvv, f7, acc[7]);    \
        float kl = (j & 4) ? ((j & 2) ? ((j & 1) ? f7 : f6) : ((j & 1) ? f5 : f4)) \
                           : ((j & 2) ? ((j & 1) ? f3 : f2) : ((j & 1) ? f1 : f0)); \
        kacc = fmaf(w, kl, kacc);                                          \
    }

    for (int c = s0; c < s1; c += 64) {
        const int m = min(64, s1 - c);
        const int idx = c + (l < m ? l : m - 1);
        const int srcv = csr_src[idx];
        const float wv = csr_w[idx];
        int e = 0;
        for (; e + 4 <= m; e += 4) {
            int sA = rdl(srcv, e), sB = rdl(srcv, e + 1), sC = rdl(srcv, e + 2), sD = rdl(srcv, e + 3);
            uint4 kA = *(const uint4*)(K0h + sA * 64 + hb);
            uint4 kB = *(const uint4*)(K0h + sB * 64 + hb);
            uint4 kC = *(const uint4*)(K0h + sC * 64 + hb);
            uint4 kD = *(const uint4*)(K0h + sD * 64 + hb);
            __fp16 vA = Vh[sA * 64 + l], vB = Vh[sB * 64 + l], vC = Vh[sC * 64 + l], vD = Vh[sD * 64 + l];
            H1_BODY(kA, vA, e)
            H1_BODY(kB, vB, e + 1)
            H1_BODY(kC, vC, e + 2)
            H1_BODY(kD, vD, e + 3)
        }
        for (; e < m; e++) {
            int sA = rdl(srcv, e);
            uint4 kA = *(const uint4*)(K0h + sA * 64 + hb);
            __fp16 vA = Vh[sA * 64 + l];
            H1_BODY(kA, vA, e)
        }
    }
#undef H1_BODY

#ifdef M1FP8
    unsigned int w0 = 0, w1 = 0;
    w0 = __builtin_amdgcn_cvt_pk_fp8_f32(acc[0], acc[1], w0, false);
    w0 = __builtin_amdgcn_cvt_pk_fp8_f32(acc[2], acc[3], w0, true);
    w1 = __builtin_amdgcn_cvt_pk_fp8_f32(acc[4], acc[5], w1, false);
    w1 = __builtin_amdgcn_cvt_pk_fp8_f32(acc[6], acc[7], w1, true);
    uint2 o2; o2.x = w0; o2.y = w1;
    *(uint2*)(M1h + (size_t)n * M1_STRIDE + l * M1_LANE) = o2;
#else
    uint4 o;
    o.x = pkh(acc[0], acc[1]); o.y = pkh(acc[2], acc[3]);
    o.z = pkh(acc[4], acc[5]); o.w = pkh(acc[6], acc[7]);
    *(uint4*)(M1h + (size_t)n * M1_STRIDE + l * M1_LANE) = o;
#endif
    K1h[n * 64 + l] = (_Float16)kacc;
}

// ---------------------------------------------------------------------------
// Hop 2 + finalize. One node per wave, 128-thr blocks. Lane l = (h, j').
// 8-wide manual batching: ~16 loads in flight per wave.
__global__ __launch_bounds__(128) void k_hop2f(const float* __restrict__ Q,
                                               const unsigned int* __restrict__ M1h,
                                               const _Float16* __restrict__ K1h,
                                               const _Float16* __restrict__ Vh,
                                               const int* __restrict__ rowptr,
                                               const int* __restrict__ csr_src,
                                               const float* __restrict__ csr_w,
                                               const void* __restrict__ Wo, const void* __restrict__ bo,
                                               const void* __restrict__ hopwise,
                                               const void* __restrict__ headwise,
                                               void* __restrict__ out, const int* __restrict__ cnt) {
    const bool bf = (cnt[0] < 16);
    const int l = threadIdx.x & 63;
    const int n = blockIdx.x * 2 + (threadIdx.x >> 6);
    const int hb = l & 56, h = l >> 3;
    const float4 qa = *(const float4*)(Q + n * 64 + hb);
    const float4 qb = *(const float4*)(Q + n * 64 + hb + 4);
    const float qown = Q[n * 64 + l];
    float hacc = 0.0f, sk = 0.0f;
    const int s0 = rowptr[n], s1 = rowptr[n + 1];

#ifdef M1FP8
#define H2_DOT(MU, DST)                                                    \
    {                                                                      \
        floatx2 a0 = __builtin_amdgcn_cvt_pk_f32_fp8(MU.x, false);         \
        floatx2 a1 = __builtin_amdgcn_cvt_pk_f32_fp8(MU.x, true);          \
        floatx2 a2 = __builtin_amdgcn_cvt_pk_f32_fp8(MU.y, false);         \
        floatx2 a3 = __builtin_amdgcn_cvt_pk_f32_fp8(MU.y, true);          \
        DST = qa.x * a0.x;                                                 \
        DST = fmaf(qa.y, a0.y, DST); DST = fmaf(qa.z, a1.x, DST);          \
        DST = fmaf(qa.w, a1.y, DST); DST = fmaf(qb.x, a2.x, DST);          \
        DST = fmaf(qb.y, a2.y, DST); DST = fmaf(qb.z, a3.x, DST);          \
        DST = fmaf(qb.w, a3.y, DST);                                       \
    }
    typedef uint2 m1vec;
#else
    const half2_t q01 = u2h(pkh(qa.x, qa.y));
    const half2_t q23 = u2h(pkh(qa.z, qa.w));
    const half2_t q45 = u2h(pkh(qb.x, qb.y));
    const half2_t q67 = u2h(pkh(qb.z, qb.w));
#define H2_DOT(MU, DST)                                                    \
    {                                                                      \
        DST = fdot2(q01, u2h(MU.x), 0.0f);                                 \
        DST = fdot2(q23, u2h(MU.y), DST);                                  \
        DST = fdot2(q45, u2h(MU.z), DST);                                  \
        DST = fdot2(q67, u2h(MU.w), DST);                                  \
    }
    typedef uint4 m1vec;
#endif

    for (int c = s0; c < s1; c += 64) {
        const int m = min(64, s1 - c);
        const int idx = c + (l < m ? l : m - 1);
        const int srcv = csr_src[idx];
        const float wv = csr_w[idx];
        int e = 0;
        for (; e + 8 <= m; e += 8) {
            int s_[8];
            m1vec m_[8];
            __fp16 k_[8];
#pragma unroll
            for (int u = 0; u < 8; u++) s_[u] = rdl(srcv, e + u);
#pragma unroll
            for (int u = 0; u < 8; u++) m_[u] = *(const m1vec*)(M1h + (size_t)s_[u] * M1_STRIDE + l * M1_LANE);
#pragma unroll
            for (int u = 0; u < 8; u++) k_[u] = K1h[s_[u] * 64 + l];
#pragma unroll
            for (int u = 0; u < 8; u++) {
                float d;
                H2_DOT(m_[u], d)
                float w = rdlf(wv, e + u);
                hacc = fmaf(w, d, hacc);
                sk = fmaf(w, (float)k_[u], sk);
            }
        }
        for (; e < m; e++) {
            int sA = rdl(srcv, e);
            m1vec mA = *(const m1vec*)(M1h + (size_t)sA * M1_STRIDE + l * M1_LANE);
            __fp16 kA = K1h[sA * 64 + l];
            float d;
            H2_DOT(mA, d)
            float w = rdlf(wv, e);
            hacc = fmaf(w, d, hacc);
            sk = fmaf(w, (float)kA, sk);
        }
    }
    m1vec mo = *(const m1vec*)(M1h + (size_t)n * M1_STRIDE + l * M1_LANE);
    float h1;
    H2_DOT(mo, h1)
#undef H2_DOT
    float c1 = qown * (float)K1h[n * 64 + l];
    float c2 = qown * sk;
#pragma unroll
    for (int dd = 1; dd < 8; dd <<= 1) {
        c1 += __shfl_xor(c1, dd);
        c2 += __shfl_xor(c2, dd);
    }
    float hw0 = ldf(hopwise, 0, bf), hw1 = ldf(hopwise, 1, bf), hw2 = ldf(hopwise, 2, bf);
    float e0 = 0.0f, e1 = 0.0f;
#pragma unroll
    for (int hh = 0; hh < 8; hh++) {
        e0 += __expf(ldf(headwise, hh * 2 + 0, bf));
        e1 += __expf(ldf(headwise, hh * 2 + 1, bf));
    }
    float g1 = hw1 * __expf(ldf(headwise, h * 2 + 0, bf)) / e0;
    float g2 = hw2 * __expf(ldf(headwise, h * 2 + 1, bf)) / e1;

    float hidden = hw0 * (float)Vh[n * 64 + l] + g1 * h1 / (c1 + CSTF) + g2 * hacc / (c2 + CSTF);

    float o = ldf(bo, l, bf);
#pragma unroll 16
    for (int k = 0; k < 64; k++) {
        float hk = __shfl(hidden, k);
        o += hk * ldf(Wo, k * 64 + l, bf);
    }
    if (bf) ((bf16*)out)[n * 64 + l] = __float2bfloat16(o);
    else    ((float*)out)[n * 64 + l] = o;
}

// ---------------------------------------------------------------------------
extern "C" void kernel_launch(void* const* d_in, const int* in_sizes, int n_in,
                              void* d_out, int out_size, void* d_ws, size_t ws_size,
                              hipStream_t stream) {
    const void* x        = d_in[0];
    const void* ei       = d_in[1];
    const void* Wq       = d_in[3];
    const void* bq       = d_in[4];
    const void* Wk       = d_in[5];
    const void* bk       = d_in[6];
    const void* Wv       = d_in[7];
    const void* bv       = d_in[8];
    const void* Wo       = d_in[9];
    const void* bo       = d_in[10];
    const void* hopwise  = d_in[11];
    const void* headwise = d_in[12];

    char* p = (char*)d_ws;
    auto alloc = [&](size_t bytes) {
        void* r = (void*)p;
        p += (bytes + 255) & ~(size_t)255;
        return r;
    };
    float* Q          = (float*)alloc((size_t)N_NODES * 64 * 4);
    float* deg_inv    = (float*)alloc((size_t)N_NODES * 4);
    _Float16* K0h     = (_Float16*)alloc((size_t)N_NODES * 64 * 2);
    _Float16* Vh      = (_Float16*)alloc((size_t)N_NODES * 64 * 2);
    _Float16* K1h     = (_Float16*)alloc((size_t)N_NODES * 64 * 2);
    unsigned int* M1h = (unsigned int*)alloc((size_t)N_NODES * 1024);
    float* csr_w      = (float*)alloc((size_t)N_EDGES * 4);
    int* csr_src      = (int*)alloc((size_t)N_EDGES * 4);
    int* rowptr       = (int*)alloc((size_t)(N_NODES + 1) * 4);
    int* zz           = (int*)alloc(((size_t)2 * N_NODES + 64) * 4);
    int* deg  = zz;
    int* fill = zz + N_NODES;
    int* cnt  = zz + 2 * N_NODES;

    (void)hipMemsetAsync(zz, 0, ((size_t)2 * N_NODES + 64) * 4, stream);

    const int EB = (N_EDGES + 255) / 256;  // 1250

    k_p1<<<EB, 256, 0, stream>>>((const unsigned int*)x, ei, deg, cnt);
    k_scan<<<1, 1024, 0, stream>>>(deg, rowptr, deg_inv);
    k_p2<<<QKV_BLOCKS + EB, 256, 0, stream>>>(x, Wq, bq, Wk, bk, Wv, bv, Q, K0h, Vh,
                                              ei, deg_inv, rowptr, fill, csr_src, csr_w, cnt);
    k_hop1<<<N_NODES / 2, 128, 0, stream>>>(K0h, Vh, rowptr, csr_src, csr_w, M1h, K1h);
    k_hop2f<<<N_NODES / 2, 128, 0, stream>>>(Q, M1h, K1h, Vh, rowptr, csr_src, csr_w,
                                             Wo, bo, hopwise, headwise, d_out, cnt);
}